// Round 5
// baseline (444.046 us; speedup 1.0000x reference)
//
#include <hip/hip_runtime.h>
#include <hip/hip_bf16.h>

#define HW_   (512 * 512)
#define B_    4
#define D_    64
#define NPIX  (B_ * HW_)          // 1048576
#define NW    19                  // within channels used (20 - 1)
#define NC    26                  // cross channels used  (27 - 1)
#define NLAB  45
#define NSEG  20
#define WSTRIDE 48                // padded row stride of transposed weights
#define THREADS 256

// ---- macro label lists (named scalars only; no arrays anywhere) ----
#define LW(X)  X(0)X(1)X(2)X(3)X(4)X(5)X(6)X(7)X(8)X(9)X(10)X(11)X(12)X(13)X(14)X(15)X(16)X(17)X(18)
#define LC(X)  X(19)X(20)X(21)X(22)X(23)X(24)X(25)X(26)X(27)X(28)X(29)X(30)X(31)X(32)X(33)X(34)X(35)X(36)X(37)X(38)X(39)X(40)X(41)X(42)X(43)X(44)
#define LA(X)  LW(X) LC(X)

// wT[c][n] = weight of label n at channel c (labels interleaved: 0..18 within, 19..44 cross)
__global__ void transpose_w(const float* __restrict__ wW, const float* __restrict__ wC,
                            float* __restrict__ wT) {
    int i = blockIdx.x * 256 + threadIdx.x;
    if (i < D_ * NLAB) {
        int c = i / NLAB, n = i - c * NLAB;
        wT[c * WSTRIDE + n] = (n < NW) ? wW[n * D_ + c] : wC[(n - NW) * D_ + c];
    }
}

__global__ __launch_bounds__(THREADS)
__attribute__((amdgpu_waves_per_eu(6, 6)))   // pin target: 85-VGPR budget, no spill-for-occupancy path
void fused_embed(const float* __restrict__ enc, const float* __restrict__ wT,
                 const int* __restrict__ targ, float* __restrict__ out)
{
    __shared__ float sCent[NSEG][D_ + 1];  // +1 pad: bank = lab + c (mod 32)
    __shared__ int   sCount[NSEG];
    __shared__ float sRed[THREADS / 64];

    const int tid = threadIdx.x;
    for (int i = tid; i < NSEG * (D_ + 1); i += THREADS) (&sCent[0][0])[i] = 0.f;
    if (tid < NSEG) sCount[tid] = 0;
    __syncthreads();

    const int p   = blockIdx.x * THREADS + tid;    // this thread's pixel
    const int b   = (blockIdx.x * THREADS) / HW_;  // block never straddles images
    const int hw0 = p - b * HW_;
    const float* fp = enc + (size_t)b * (D_ * HW_) + hw0;
    const int lab = targ[p];

#define DECL_ACC(n) float a##n = 0.f;
    LA(DECL_ACC)
#undef DECL_ACC

    // channel-serial: per iteration live state = 45 accs + 2 features.
    // weight row wr[0..44] is contiguous & wave-uniform -> merged s_load_dwordx16.
    float fcur = fp[0];
#pragma unroll 1
    for (int c = 0; c < D_ - 1; ++c) {
        float fnext = fp[(size_t)(c + 1) * HW_];   // prefetch next channel
        const float* wr = wT + c * WSTRIDE;
#define FMA1(n) a##n = fmaf(fcur, wr[n], a##n);
        LA(FMA1)
#undef FMA1
        atomicAdd(&sCent[lab][c], fcur);           // ds_add_f32, no return
        fcur = fnext;
    }
    {
        const float* wr = wT + (D_ - 1) * WSTRIDE;
#define FMA1(n) a##n = fmaf(fcur, wr[n], a##n);
        LA(FMA1)
#undef FMA1
        atomicAdd(&sCent[lab][D_ - 1], fcur);
    }
    atomicAdd(&sCount[lab], 1);

    // ---- entropy WITHOUT max-shift: logits ~ N(0,1), |logit| < ~8 << 88, exp safe.
    // -sum p log p = log S - (sum e^a * a)/S
    float lossAcc;
    {
        float S = 0.f, Wt = 0.f;
#define ES(n) { float e = __expf(a##n); S += e; Wt = fmaf(e, a##n, Wt); }
        LW(ES)
#undef ES
        lossAcc = __logf(S) - Wt / S;
    }
    {
        float S = 0.f, Wt = 0.f;
#define ES(n) { float e = __expf(a##n); S += e; Wt = fmaf(e, a##n, Wt); }
        LC(ES)
#undef ES
        lossAcc += __logf(S) - Wt / S;
    }

    // wave reduce (64 lanes)
#pragma unroll
    for (int off = 32; off; off >>= 1) lossAcc += __shfl_down(lossAcc, off);
    if ((tid & 63) == 0) sRed[tid >> 6] = lossAcc;
    __syncthreads();
    if (tid == 0) {
        float s = 0.f;
#pragma unroll
        for (int w = 0; w < THREADS / 64; ++w) s += sRed[w];
        atomicAdd(out, s * (0.5f / (float)NPIX));
    }

    // flush centroids + counts (counts written as float: harness reads f32)
    for (int i = tid; i < NSEG * D_; i += THREADS) {
        int n = i >> 6, d = i & 63;
        atomicAdd(&out[1 + i], sCent[n][d]);
    }
    if (tid < NSEG) atomicAdd(&out[1 + NSEG * D_ + tid], (float)sCount[tid]);
}

extern "C" void kernel_launch(void* const* d_in, const int* in_sizes, int n_in,
                              void* d_out, int out_size, void* d_ws, size_t ws_size,
                              hipStream_t stream) {
    const float* enc = (const float*)d_in[0];
    const float* wW  = (const float*)d_in[1];
    const float* wC  = (const float*)d_in[2];
    const int*   targ = (const int*)d_in[3];
    float* out = (float*)d_out;
    float* wT  = (float*)d_ws;                 // 64*48*4 = 12288 B of scratch

    // d_out is poisoned 0xAA once and never re-poisoned; we accumulate with
    // atomics, so zero it every call (memset node is graph-capturable).
    hipMemsetAsync(d_out, 0, (size_t)out_size * sizeof(float), stream);

    transpose_w<<<dim3((D_ * NLAB + 255) / 256), dim3(256), 0, stream>>>(wW, wC, wT);
    fused_embed<<<dim3(NPIX / THREADS), dim3(THREADS), 0, stream>>>(enc, wT, targ, out);
}

// Round 6
// 380.529 us; speedup vs baseline: 1.1669x; 1.1669x over previous
//
#include <hip/hip_runtime.h>
#include <hip/hip_bf16.h>

#define HW_   (512 * 512)
#define B_    4
#define D_    64
#define NPIX  (B_ * HW_)          // 1048576
#define NW    19                  // within channels used (20 - 1)
#define NC    26                  // cross channels used  (27 - 1)
#define NSEG  20
#define SW_   20                  // padded stride of wTW rows (floats)
#define SC_   28                  // padded stride of wTC rows (floats)
#define THREADS 256

// ---- macro index lists (named scalars only) ----
#define L19(X) X(0)X(1)X(2)X(3)X(4)X(5)X(6)X(7)X(8)X(9)X(10)X(11)X(12)X(13)X(14)X(15)X(16)X(17)X(18)
#define L26(X) X(0)X(1)X(2)X(3)X(4)X(5)X(6)X(7)X(8)X(9)X(10)X(11)X(12)X(13)X(14)X(15)X(16)X(17)X(18)X(19)X(20)X(21)X(22)X(23)X(24)X(25)

// wTW[c][n] = wW[n][c] (channel-major: per-channel rows contiguous for merged s_load)
__global__ void transpose_w(const float* __restrict__ wW, const float* __restrict__ wC,
                            float* __restrict__ ws) {
    int i = blockIdx.x * 256 + threadIdx.x;
    float* wTW = ws;                 // 64 * 20
    float* wTC = ws + D_ * SW_;      // 64 * 28
    if (i < D_ * SW_) {
        int c = i / SW_, n = i - c * SW_;
        wTW[i] = (n < NW) ? wW[n * D_ + c] : 0.f;
    }
    if (i < D_ * SC_) {
        int c = i / SC_, n = i - c * SC_;
        wTC[i] = (n < NC) ? wC[n * D_ + c] : 0.f;
    }
}

__global__ __launch_bounds__(THREADS)
void fused_embed(const float* __restrict__ enc, const float* __restrict__ ws,
                 const int* __restrict__ targ, float* __restrict__ out)
{
    const float* wTW = ws;
    const float* wTC = ws + D_ * SW_;

    __shared__ float sCent[NSEG][D_ + 1];   // +1 pad: bank = lab + c (mod 32)
    __shared__ int   sCount[NSEG];
    __shared__ float sRed[THREADS / 64];

    const int tid = threadIdx.x;
    for (int i = tid; i < NSEG * (D_ + 1); i += THREADS) (&sCent[0][0])[i] = 0.f;
    if (tid < NSEG) sCount[tid] = 0;
    __syncthreads();

    const int p   = blockIdx.x * THREADS + tid;    // 1 pixel per thread
    const int b   = (blockIdx.x * THREADS) / HW_;  // block never straddles images
    const int hw0 = p - b * HW_;
    const float* fp = enc + (size_t)b * (D_ * HW_) + hw0;
    const int lab = targ[p];

    float lossAcc = 0.f;

    // ================= PASS 1: within (19 accs) + centroids =================
    {
#define DECL(n) float a##n = 0.f;
        L19(DECL)
#undef DECL
#pragma unroll 1
        for (int c = 0; c < D_; c += 2) {
            float f0 = fp[(size_t)c * HW_];
            float f1 = fp[(size_t)(c + 1) * HW_];
            const float* r0 = wTW + c * SW_;       // uniform -> merged s_load
            const float* r1 = r0 + SW_;
#define FMA2(n) { a##n = fmaf(r0[n], f0, a##n); a##n = fmaf(r1[n], f1, a##n); }
            L19(FMA2)
#undef FMA2
            atomicAdd(&sCent[lab][c], f0);         // ds_add_f32, no return
            atomicAdd(&sCent[lab][c + 1], f1);
        }
        atomicAdd(&sCount[lab], 1);

        // entropy, no max-shift (logits ~ N(0,1); validated in R5): log S - (Σ a e^a)/S
        float S = 0.f, Wt = 0.f;
#define ES(n) { float e = __expf(a##n); S += e; Wt = fmaf(e, a##n, Wt); }
        L19(ES)
#undef ES
        lossAcc += __logf(S) - Wt / S;
    }

    // ================= PASS 2: cross (26 accs), features re-read from L2 =====
    {
#define DECL(n) float a##n = 0.f;
        L26(DECL)
#undef DECL
#pragma unroll 1
        for (int c = 0; c < D_; c += 2) {
            float f0 = fp[(size_t)c * HW_];
            float f1 = fp[(size_t)(c + 1) * HW_];
            const float* r0 = wTC + c * SC_;
            const float* r1 = r0 + SC_;
#define FMA2(n) { a##n = fmaf(r0[n], f0, a##n); a##n = fmaf(r1[n], f1, a##n); }
            L26(FMA2)
#undef FMA2
        }
        float S = 0.f, Wt = 0.f;
#define ES(n) { float e = __expf(a##n); S += e; Wt = fmaf(e, a##n, Wt); }
        L26(ES)
#undef ES
        lossAcc += __logf(S) - Wt / S;
    }

    // ---- wave + block reduce of loss ----
#pragma unroll
    for (int off = 32; off; off >>= 1) lossAcc += __shfl_down(lossAcc, off);
    if ((tid & 63) == 0) sRed[tid >> 6] = lossAcc;
    __syncthreads();
    if (tid == 0) {
        float s = 0.f;
#pragma unroll
        for (int w = 0; w < THREADS / 64; ++w) s += sRed[w];
        atomicAdd(out, s * (0.5f / (float)NPIX));
    }

    // ---- flush centroids + counts (counts as float; harness reads f32) ----
    for (int i = tid; i < NSEG * D_; i += THREADS) {
        int n = i >> 6, d = i & 63;
        atomicAdd(&out[1 + i], sCent[n][d]);
    }
    if (tid < NSEG) atomicAdd(&out[1 + NSEG * D_ + tid], (float)sCount[tid]);
}

extern "C" void kernel_launch(void* const* d_in, const int* in_sizes, int n_in,
                              void* d_out, int out_size, void* d_ws, size_t ws_size,
                              hipStream_t stream) {
    const float* enc = (const float*)d_in[0];
    const float* wW  = (const float*)d_in[1];
    const float* wC  = (const float*)d_in[2];
    const int*   targ = (const int*)d_in[3];
    float* out = (float*)d_out;
    float* ws  = (float*)d_ws;                 // (64*20 + 64*28) * 4 = 12288 B

    // d_out poisoned 0xAA once, never re-poisoned; we accumulate with atomics,
    // so zero it every call (memset node is graph-capturable).
    hipMemsetAsync(d_out, 0, (size_t)out_size * sizeof(float), stream);

    transpose_w<<<dim3((D_ * SC_ + 255) / 256), dim3(256), 0, stream>>>(wW, wC, ws);
    fused_embed<<<dim3(NPIX / THREADS), dim3(THREADS), 0, stream>>>(enc, ws, targ, out);
}